// Round 3
// baseline (2132.644 us; speedup 1.0000x reference)
//
#include <hip/hip_runtime.h>
#include <hip/hip_fp16.h>

// MAHGN: 2-layer hetero GAT, fp32 math / fp16 message payload.
// Round 8: R7 structure, latency fixes in the gather:
//  - no cross-lane shfl: every lane loads the a_s quad (broadcast float4) and
//    computes all 4 head exps itself -> per-edge chain is load->VALU only.
//  - sAgg[16][4][68] layout: head rows 68 floats apart -> epilogue reads
//    conflict-free (R7 had 4-way conflicts on every read, 3.2M/dispatch).
//  - depth-2 register prefetch of (row, a_s, xh) in the edge loop.

static constexpr int kNUser = 200000;
static constexpr int kNArt  = 100000;
static constexpr int kNCat  = 500;
static constexpr size_t SZ_U = (size_t)kNUser * 64;
static constexpr size_t SZ_A = (size_t)kNArt * 64;
static constexpr size_t SZ_C = (size_t)kNCat * 64;
static constexpr size_t SZ_X = SZ_U + SZ_A + SZ_C;
static constexpr int CHUNK = 4096;

__device__ __forceinline__ uint32_t packh2(float a, float b) {
  __half2 t = __floats2half2_rn(a, b);
  return *reinterpret_cast<uint32_t*>(&t);
}
__device__ __forceinline__ float2 unpackh2(uint32_t u) {
  __half2 t = *reinterpret_cast<__half2*>(&u);
  return __half22float2(t);
}

// ---------------- fold: vs[k,h] = sum_c W[k][h*16+c]*att[h*16+c] ----------------
// grid 16 = (l*8+t); writes fold[(lt*2+sd)*256 + k*4 + h] for sd=0(src),1(dst)
__global__ void k_fold(const float* __restrict__ Wsrc, const float* __restrict__ Wdst,
                       const float* __restrict__ attS, const float* __restrict__ attD,
                       float* __restrict__ fold)
{
  int lt = blockIdx.x;
  int tid = threadIdx.x;
  int k = tid >> 2, h = tid & 3;
  const float* Ws = Wsrc + (size_t)lt * 4096;
  const float* Wd = Wdst + (size_t)lt * 4096;
  const float* aS = attS + (size_t)lt * 64;
  const float* aD = attD + (size_t)lt * 64;
  float s = 0.f, d = 0.f;
  #pragma unroll
  for (int c = 0; c < 16; ++c) {
    s += Ws[k * 64 + h * 16 + c] * aS[h * 16 + c];
    d += Wd[k * 64 + h * 16 + c] * aD[h * 16 + c];
  }
  fold[((size_t)lt * 2 + 0) * 256 + tid] = s;
  fold[((size_t)lt * 2 + 1) * 256 + tid] = d;
}

// summed bias per (layer, dst-type): user {1,2,3,7}, article {0,5}, category {4,6}
__global__ void k_bsum(const float* __restrict__ bias, float* __restrict__ bact) {
  int l = blockIdx.x;
  int tid = threadIdx.x;            // 192
  int d = tid >> 6, c = tid & 63;
  const float* b = bias + (size_t)l * 512;
  float v;
  if (d == 0)      v = b[64 + c] + b[128 + c] + b[192 + c] + b[448 + c];
  else if (d == 1) v = b[c] + b[320 + c];
  else             v = b[256 + c] + b[384 + c];
  bact[((size_t)l * 3 + d) * 64 + c] = v;
}

// ---------------- k_attn: per node type, all folded GEMVs + fp16 cast ----------------
template <int NV>
__global__ __launch_bounds__(256) void k_attn(const float* __restrict__ x,
    uint4* __restrict__ xh, const float* __restrict__ fold,
    int4 sa, int4 sb, float* __restrict__ aout, int Ns)
{
  __shared__ float sV[NV * 256];
  int tid = threadIdx.x;
  const int slots[8] = {sa.x, sa.y, sa.z, sa.w, sb.x, sb.y, sb.z, sb.w};
  #pragma unroll
  for (int v = 0; v < NV; ++v)
    sV[v * 256 + tid] = fold[(size_t)slots[v] * 256 + tid];
  __syncthreads();
  int n = blockIdx.x * 256 + tid;
  if (n >= Ns) return;
  const float4* xp = (const float4*)(x + (size_t)n * 64);
  float4 xr[16];
  #pragma unroll
  for (int q = 0; q < 16; ++q) xr[q] = xp[q];
  uint4* dst = xh + (size_t)n * 8;
  #pragma unroll
  for (int q = 0; q < 8; ++q) {
    uint4 u;
    u.x = packh2(xr[2 * q].x, xr[2 * q].y);
    u.y = packh2(xr[2 * q].z, xr[2 * q].w);
    u.z = packh2(xr[2 * q + 1].x, xr[2 * q + 1].y);
    u.w = packh2(xr[2 * q + 1].z, xr[2 * q + 1].w);
    dst[q] = u;
  }
  #pragma unroll
  for (int v = 0; v < NV; ++v) {
    float a0 = 0.f, a1 = 0.f, a2 = 0.f, a3 = 0.f;
    #pragma unroll
    for (int q = 0; q < 16; ++q) {
      const float* xf = &xr[q].x;
      #pragma unroll
      for (int j = 0; j < 4; ++j) {
        int k = q * 4 + j;
        float4 vv = *(const float4*)&sV[v * 256 + k * 4];
        float xk = xf[j];
        a0 += xk * vv.x; a1 += xk * vv.y; a2 += xk * vv.z; a3 += xk * vv.w;
      }
    }
    *(float4*)(aout + (size_t)n * (NV * 4) + v * 4) = make_float4(a0, a1, a2, a3);
  }
}

// ---------------- CSR build: two-level LDS multisplit (unchanged) ----------------

__global__ __launch_bounds__(256) void k_bhist(const int* __restrict__ col, int E,
    int nblk, int nbin, int shift, int* __restrict__ bh)
{
  __shared__ int h[1024];
  int tid = threadIdx.x;
  for (int j = tid; j < nbin; j += 256) h[j] = 0;
  __syncthreads();
  int b = blockIdx.x;
  int lo = b * CHUNK, hi = min(E, lo + CHUNK);
  for (int i = lo + tid; i < hi; i += 256) atomicAdd(&h[col[i] >> shift], 1);
  __syncthreads();
  for (int j = tid; j < nbin; j += 256) bh[j * nblk + b] = h[j];   // bin-major
}

__global__ __launch_bounds__(256) void k_s1(const int* __restrict__ a,
    int* __restrict__ bsum, int n)
{
  __shared__ int tmp[256];
  int t = threadIdx.x;
  int base = blockIdx.x * 4096 + t * 16;
  int s = 0;
  #pragma unroll
  for (int i = 0; i < 16; ++i) { int idx = base + i; if (idx < n) s += a[idx]; }
  tmp[t] = s;
  __syncthreads();
  for (int off = 128; off > 0; off >>= 1) {
    if (t < off) tmp[t] += tmp[t + off];
    __syncthreads();
  }
  if (t == 0) bsum[blockIdx.x] = tmp[0];
}

__global__ __launch_bounds__(1024) void k_s2(int* __restrict__ bsum, int nb) {
  __shared__ int tmp[1024];
  int t = threadIdx.x;
  int v = (t < nb) ? bsum[t] : 0;
  tmp[t] = v;
  __syncthreads();
  for (int off = 1; off < 1024; off <<= 1) {
    int u = (t >= off) ? tmp[t - off] : 0;
    __syncthreads();
    tmp[t] += u;
    __syncthreads();
  }
  if (t < nb) bsum[t] = tmp[t] - v;   // exclusive
}

__global__ __launch_bounds__(256) void k_s3(int* __restrict__ a,
    const int* __restrict__ bsum, int n)
{
  __shared__ int tw[256];
  int t = threadIdx.x;
  int base = blockIdx.x * 4096 + t * 16;
  int v[16];
  int s = 0;
  #pragma unroll
  for (int i = 0; i < 16; ++i) { int idx = base + i; v[i] = (idx < n) ? a[idx] : 0; s += v[i]; }
  tw[t] = s;
  __syncthreads();
  for (int off = 1; off < 256; off <<= 1) {
    int u = (t >= off) ? tw[t - off] : 0;
    __syncthreads();
    tw[t] += u;
    __syncthreads();
  }
  int excl = bsum[blockIdx.x] + tw[t] - s;
  #pragma unroll
  for (int i = 0; i < 16; ++i) {
    int idx = base + i;
    if (idx < n) { a[idx] = excl; excl += v[i]; }
  }
}

__global__ void k_binbase(const int* __restrict__ bh, int nblk, int nbin, int E,
                          int* __restrict__ binbase)
{
  int j = blockIdx.x * 256 + threadIdx.x;
  if (j < nbin) binbase[j] = bh[(size_t)j * nblk];
  if (j == nbin) binbase[nbin] = E;
}

__global__ __launch_bounds__(256) void k_bscat(const int* __restrict__ row,
    const int* __restrict__ col, int E, int nblk, int nbin, int shift,
    const int* __restrict__ bh,
    int* __restrict__ trow, int* __restrict__ tcol)
{
  __shared__ int cur[1024];
  int tid = threadIdx.x;
  int b = blockIdx.x;
  for (int j = tid; j < nbin; j += 256) cur[j] = bh[j * nblk + b];
  __syncthreads();
  int lo = b * CHUNK, hi = min(E, lo + CHUNK);
  for (int i = lo + tid; i < hi; i += 256) {
    int c = col[i];
    int p = atomicAdd(&cur[c >> shift], 1);
    trow[p] = row[i];
    if (tcol) tcol[p] = c;
  }
}

__global__ __launch_bounds__(256) void k_fine(const int* __restrict__ trow,
    const int* __restrict__ tcol, const int* __restrict__ binbase,
    int* __restrict__ rowptr, int* __restrict__ rows, int Nd, int nbin)
{
  __shared__ int h[256], sc[256], cur[256];
  int tid = threadIdx.x;
  int bin = blockIdx.x;
  int s = binbase[bin], e = binbase[bin + 1];
  h[tid] = 0;
  __syncthreads();
  for (int k = s + tid; k < e; k += 256) atomicAdd(&h[tcol[k] & 255], 1);
  __syncthreads();
  int own = h[tid];
  sc[tid] = own;
  __syncthreads();
  for (int off = 1; off < 256; off <<= 1) {
    int t = (tid >= off) ? sc[tid - off] : 0;
    __syncthreads();
    sc[tid] += t;
    __syncthreads();
  }
  int excl = sc[tid] - own;
  int dst = bin * 256 + tid;
  if (dst < Nd) rowptr[dst] = s + excl;
  cur[tid] = s + excl;
  if (bin == 0 && tid == 0) rowptr[Nd] = binbase[nbin];
  __syncthreads();
  for (int k = s + tid; k < e; k += 256) {
    int p = atomicAdd(&cur[tcol[k] & 255], 1);
    rows[p] = trow[k];
  }
}

__global__ void k_rp(const int* __restrict__ binbase, int* __restrict__ rowptr, int Nd) {
  int i = blockIdx.x * 256 + threadIdx.x;
  if (i <= Nd) rowptr[i] = binbase[i];
}

// ---------------- gather: per-head x aggregation + fused W epilogue ----------------
// 256 thr = 16 groups x 16 lanes; group g handles dst n = blockIdx*16+g.
// Lane l owns dims l*4..l*4+3 and computes all 4 head weights itself from a
// broadcast a_s float4 (no cross-lane ops in the edge loop).
// mode: 0 = accumulate (RMW), 1 = first (plain write), 2 = last (RMW + bias + leaky)
__global__ __launch_bounds__(256) void k_gat16(const int* __restrict__ rowptr,
    const int* __restrict__ rows, const float* __restrict__ aS, int sS,
    const float* __restrict__ aD, int sD, const uint32_t* __restrict__ xh,
    const float* __restrict__ W, float* __restrict__ out, int Nd,
    int mode, const float* __restrict__ bact)
{
  __shared__ float sAgg[16][4][68];   // 17.4 KB; [group][head][dim+pad]
  int tid = threadIdx.x;
  int g = tid >> 4, l = tid & 15;
  int n = blockIdx.x * 16 + g;
  float acc[4][4] = {{0.f,0.f,0.f,0.f},{0.f,0.f,0.f,0.f},{0.f,0.f,0.f,0.f},{0.f,0.f,0.f,0.f}};
  float den[4] = {0.f, 0.f, 0.f, 0.f};
  if (n < Nd) {
    float4 ad4 = *(const float4*)(aD + (size_t)n * sD);
    int start = rowptr[n], end = rowptr[n + 1];
    int k = start;
    float4 asN = make_float4(0.f, 0.f, 0.f, 0.f);
    uint2 xrN = make_uint2(0, 0);
    if (k < end) {
      int r0 = rows[k];
      asN = *(const float4*)(aS + (size_t)r0 * sS);
      xrN = *(const uint2*)(xh + (size_t)r0 * 32 + l * 2);
    }
    for (; k < end; ++k) {
      float4 as4 = asN;
      uint2 xr = xrN;
      if (k + 1 < end) {                 // depth-2 prefetch
        int r2 = rows[k + 1];
        asN = *(const float4*)(aS + (size_t)r2 * sS);
        xrN = *(const uint2*)(xh + (size_t)r2 * 32 + l * 2);
      }
      float2 x01 = unpackh2(xr.x);
      float2 x23 = unpackh2(xr.y);
      const float* asf = &as4.x;
      const float* adf = &ad4.x;
      #pragma unroll
      for (int m = 0; m < 4; ++m) {
        float v = asf[m] + adf[m];
        v = v >= 0.f ? v : 0.2f * v;
        float p = __expf(v);     // logits O(1): plain exp, no online max needed
        den[m] += p;
        acc[m][0] += p * x01.x; acc[m][1] += p * x01.y;
        acc[m][2] += p * x23.x; acc[m][3] += p * x23.y;
      }
    }
  }
  #pragma unroll
  for (int m = 0; m < 4; ++m) {
    float inv = 1.f / (den[m] + 1e-16f);
    *(float4*)&sAgg[g][m][l * 4] = make_float4(
        acc[m][0] * inv, acc[m][1] * inv, acc[m][2] * inv, acc[m][3] * inv);
  }
  __syncthreads();
  // epilogue GEMM: out[n, c] += sum_k agg[n, head(c), k] * W[k][c]
  // W is 16 KB, identical across blocks -> L1-resident.
  int c4 = tid & 15, hh = c4 >> 2;
  float r0 = 0.f, r1 = 0.f, r2 = 0.f, r3 = 0.f;
  #pragma unroll 8
  for (int k = 0; k < 64; ++k) {
    float a = sAgg[g][hh][k];
    float4 wv = *(const float4*)(W + k * 64 + c4 * 4);
    r0 += a * wv.x; r1 += a * wv.y; r2 += a * wv.z; r3 += a * wv.w;
  }
  if (n < Nd) {
    float4* op = (float4*)(out + (size_t)n * 64) + c4;
    float4 pv;
    if (mode != 1) {
      pv = *op;
      pv.x += r0; pv.y += r1; pv.z += r2; pv.w += r3;
    } else {
      pv = make_float4(r0, r1, r2, r3);
    }
    if (mode == 2) {
      float4 bb = ((const float4*)bact)[c4];
      pv.x += bb.x; pv.y += bb.y; pv.z += bb.z; pv.w += bb.w;
      pv.x = pv.x >= 0.f ? pv.x : 0.01f * pv.x;
      pv.y = pv.y >= 0.f ? pv.y : 0.01f * pv.y;
      pv.z = pv.z >= 0.f ? pv.z : 0.01f * pv.z;
      pv.w = pv.w >= 0.f ? pv.w : 0.01f * pv.w;
    }
    *op = pv;
  }
}

// big-degree path: one block per dst (Nd <= 512), 16 subgroups stride edges.
__global__ __launch_bounds__(256) void k_gatB(const int* __restrict__ rowptr,
    const int* __restrict__ rows, const float* __restrict__ aS, int sS,
    const float* __restrict__ aD, int sD, const uint32_t* __restrict__ xh,
    const float* __restrict__ W, float* __restrict__ out,
    int mode, const float* __restrict__ bact)
{
  __shared__ float sAgg[16][4][68];
  __shared__ float sDen[16][4];
  __shared__ float sRes[256];
  int n = blockIdx.x;
  int tid = threadIdx.x;
  int g = tid >> 4, l = tid & 15;
  float4 ad4 = *(const float4*)(aD + (size_t)n * sD);
  int start = rowptr[n], end = rowptr[n + 1];
  float acc[4][4] = {{0.f,0.f,0.f,0.f},{0.f,0.f,0.f,0.f},{0.f,0.f,0.f,0.f},{0.f,0.f,0.f,0.f}};
  float den[4] = {0.f, 0.f, 0.f, 0.f};
  int k = start + g;
  float4 asN = make_float4(0.f, 0.f, 0.f, 0.f);
  uint2 xrN = make_uint2(0, 0);
  if (k < end) {
    int r0 = rows[k];
    asN = *(const float4*)(aS + (size_t)r0 * sS);
    xrN = *(const uint2*)(xh + (size_t)r0 * 32 + l * 2);
  }
  for (; k < end; k += 16) {
    float4 as4 = asN;
    uint2 xr = xrN;
    if (k + 16 < end) {
      int r2 = rows[k + 16];
      asN = *(const float4*)(aS + (size_t)r2 * sS);
      xrN = *(const uint2*)(xh + (size_t)r2 * 32 + l * 2);
    }
    float2 x01 = unpackh2(xr.x);
    float2 x23 = unpackh2(xr.y);
    const float* asf = &as4.x;
    const float* adf = &ad4.x;
    #pragma unroll
    for (int m = 0; m < 4; ++m) {
      float v = asf[m] + adf[m];
      v = v >= 0.f ? v : 0.2f * v;
      float p = __expf(v);
      den[m] += p;
      acc[m][0] += p * x01.x; acc[m][1] += p * x01.y;
      acc[m][2] += p * x23.x; acc[m][3] += p * x23.y;
    }
  }
  #pragma unroll
  for (int m = 0; m < 4; ++m)
    *(float4*)&sAgg[g][m][l * 4] =
        make_float4(acc[m][0], acc[m][1], acc[m][2], acc[m][3]);
  if (l == 0) {
    sDen[g][0] = den[0]; sDen[g][1] = den[1]; sDen[g][2] = den[2]; sDen[g][3] = den[3];
  }
  __syncthreads();
  int hh = tid >> 6, dim = tid & 63;
  float A = 0.f;
  #pragma unroll
  for (int gg = 0; gg < 16; ++gg) A += sAgg[gg][hh][dim];
  float D = 0.f;
  #pragma unroll
  for (int gg = 0; gg < 16; ++gg) D += sDen[gg][hh];
  sRes[tid] = A / (D + 1e-16f);     // [head*64 + dim]
  __syncthreads();
  if (tid < 64) {
    int hc = tid >> 4;
    float r = 0.f;
    #pragma unroll 8
    for (int k2 = 0; k2 < 64; ++k2) r += sRes[hc * 64 + k2] * W[k2 * 64 + tid];
    size_t idx = (size_t)n * 64 + tid;
    float v = (mode == 1) ? r : out[idx] + r;
    if (mode == 2) {
      v += bact[tid];
      v = v >= 0.f ? v : 0.01f * v;
    }
    out[idx] = v;
  }
}

// ---------------- epilogue ----------------

__global__ void k_final(const float* __restrict__ x0, const float* __restrict__ x1,
                        const float* __restrict__ x2, float* __restrict__ out, int n)
{
  int i = blockIdx.x * blockDim.x + threadIdx.x;
  if (i < n) out[i] = (x0[i] + x1[i] + x2[i]) * (1.f / 3.f);
}

// ---------------- launch ----------------

extern "C" void kernel_launch(void* const* d_in, const int* in_sizes, int n_in,
                              void* d_out, int out_size, void* d_ws, size_t ws_size,
                              hipStream_t stream)
{
  static const int ECNT[8] = {1000000, 1000000, 500000, 500000, 100000, 100000, 500000, 500000};
  static const int ESRC[8] = {0, 1, 0, 0, 1, 2, 0, 2};   // 0=user 1=article 2=category
  static const int EDST[8] = {1, 0, 0, 0, 2, 1, 2, 0};
  // first/last gather per dst type: user first=t1 last=t7; art first=t0 last=t5; cat first=t4 last=t6
  static const int MODE[8] = {1, 1, 0, 0, 1, 2, 2, 2};
  const int NSZ[3] = {kNUser, kNArt, kNCat};

  const float* x0[3] = {(const float*)d_in[0], (const float*)d_in[1], (const float*)d_in[2]};
  const float* Wsrc = (const float*)d_in[3];
  const float* Wdst = (const float*)d_in[4];
  const float* attS = (const float*)d_in[5];
  const float* attD = (const float*)d_in[6];
  const float* bias = (const float*)d_in[7];
  const int* ei[8];
  for (int t = 0; t < 8; ++t) ei[t] = (const int*)d_in[8 + t];

  float* ws = (float*)d_ws;
  size_t off = 0;
  auto alloc = [&](size_t nelem) { float* p = ws + off; off += nelem; return p; };
  float* xb0 = alloc(SZ_X);
  float* xb1 = alloc(SZ_X);
  float* xhf = alloc(SZ_X / 2);            // fp16 copy of current x (SZ_X halves)
  float* aU  = alloc((size_t)kNUser * 32); // 8 slots x 4 heads
  float* aA  = alloc((size_t)kNArt * 16);  // 4 slots
  float* aC  = alloc((size_t)kNCat * 16);  // 4 slots
  float* fold = alloc(16 * 2 * 256);       // (l*8+t, src/dst) folded 64x4 vecs
  float* bact = alloc(2 * 3 * 64);         // summed bias per (layer, dst type)
  int* rowptrA = (int*)alloc(1001008);
  int* rowsA   = (int*)alloc(4200000);
  int* tmp_row = (int*)alloc(1000000);
  int* tmp_col = (int*)alloc(1000000);
  int* blockhist = (int*)alloc(200704);
  int* binbase   = (int*)alloc(1032);
  int* bsum      = (int*)alloc(1024);

  uint32_t* xh32 = (uint32_t*)xhf;
  uint32_t* xh_u = xh32;
  uint32_t* xh_a = xh32 + (size_t)kNUser * 32;
  uint32_t* xh_c = xh_a + (size_t)kNArt * 32;

  int* rowptr_t[8]; int* rows_t[8];
  {
    size_t ro = 0, eo = 0;
    for (int t = 0; t < 8; ++t) {
      int Nd = NSZ[EDST[t]];
      rowptr_t[t] = rowptrA + ro; ro += (size_t)Nd + 1;
      rows_t[t]   = rowsA + eo;   eo += (size_t)ECNT[t];
    }
  }

  // per-type a_s/a_d pointers into interleaved per-node-type tables
  // user slots: [t0s,t2s,t3s,t6s, t1d,t2d,t3d,t7d]; art: [t1s,t4s, t0d,t5d]; cat: [t5s,t7s, t4d,t6d]
  float* aSp[8] = {aU + 0, aA + 0, aU + 4, aU + 8, aA + 4, aC + 0, aU + 12, aC + 4};
  int    sSs[8] = {32, 16, 32, 32, 16, 16, 32, 16};
  float* aDp[8] = {aA + 8, aU + 16, aU + 20, aU + 24, aC + 8, aA + 12, aC + 12, aU + 28};
  int    sDs[8] = {16, 32, 32, 32, 16, 16, 16, 32};
  const uint32_t* xhp[8] = {xh_u, xh_a, xh_u, xh_u, xh_a, xh_c, xh_u, xh_c};

  // ---- fold attention vectors + summed biases ----
  k_fold<<<16, 256, 0, stream>>>(Wsrc, Wdst, attS, attD, fold);
  k_bsum<<<2, 192, 0, stream>>>(bias, bact);

  // ---- CSR build: two-level LDS multisplit (no global atomics) ----
  for (int t = 0; t < 8; ++t) {
    int Nd = NSZ[EDST[t]], E = ECNT[t];
    const int* row = ei[t];
    const int* col = ei[t] + E;
    int shift = (Nd <= 1024) ? 0 : 8;
    int nbin = ((Nd - 1) >> shift) + 1;
    int nblk = (E + CHUNK - 1) / CHUNK;
    int n = nbin * nblk;
    int nb2 = (n + 4095) / 4096;
    k_bhist<<<nblk, 256, 0, stream>>>(col, E, nblk, nbin, shift, blockhist);
    k_s1<<<nb2, 256, 0, stream>>>(blockhist, bsum, n);
    k_s2<<<1, 1024, 0, stream>>>(bsum, nb2);
    k_s3<<<nb2, 256, 0, stream>>>(blockhist, bsum, n);
    k_binbase<<<(nbin + 256) / 256, 256, 0, stream>>>(blockhist, nblk, nbin, E, binbase);
    if (shift == 0) {
      k_bscat<<<nblk, 256, 0, stream>>>(row, col, E, nblk, nbin, 0,
                                        blockhist, rows_t[t], nullptr);
      k_rp<<<(Nd + 256) / 256, 256, 0, stream>>>(binbase, rowptr_t[t], Nd);
    } else {
      k_bscat<<<nblk, 256, 0, stream>>>(row, col, E, nblk, nbin, 8,
                                        blockhist, tmp_row, tmp_col);
      k_fine<<<nbin, 256, 0, stream>>>(tmp_row, tmp_col, binbase,
                                       rowptr_t[t], rows_t[t], Nd, nbin);
    }
  }

  float* xb[2][3] = {{xb0, xb0 + SZ_U, xb0 + SZ_U + SZ_A},
                     {xb1, xb1 + SZ_U, xb1 + SZ_U + SZ_A}};
  const float* xcur[3] = {x0[0], x0[1], x0[2]};
  for (int l = 0; l < 2; ++l) {
    // fold-slot id for (t, sd): ((l*8+t)*2 + sd)
    auto F = [&](int t, int sd) { return (l * 8 + t) * 2 + sd; };
    int4 ua = make_int4(F(0, 0), F(2, 0), F(3, 0), F(6, 0));
    int4 ub = make_int4(F(1, 1), F(2, 1), F(3, 1), F(7, 1));
    int4 aa = make_int4(F(1, 0), F(4, 0), F(0, 1), F(5, 1));
    int4 ca = make_int4(F(5, 0), F(7, 0), F(4, 1), F(6, 1));
    k_attn<8><<<(kNUser + 255) / 256, 256, 0, stream>>>(xcur[0], (uint4*)xh_u, fold, ua, ub, aU, kNUser);
    k_attn<4><<<(kNArt + 255) / 256, 256, 0, stream>>>(xcur[1], (uint4*)xh_a, fold, aa, aa, aA, kNArt);
    k_attn<4><<<(kNCat + 255) / 256, 256, 0, stream>>>(xcur[2], (uint4*)xh_c, fold, ca, ca, aC, kNCat);
    for (int t = 0; t < 8; ++t) {
      int d = EDST[t];
      int Nd = NSZ[d];
      const float* Wt = Wsrc + (size_t)(l * 8 + t) * 4096;
      int mode = MODE[t];
      const float* ba = (mode == 2) ? bact + ((size_t)l * 3 + d) * 64 : nullptr;
      if (Nd <= 512)
        k_gatB<<<Nd, 256, 0, stream>>>(rowptr_t[t], rows_t[t], aSp[t], sSs[t],
                                       aDp[t], sDs[t], xhp[t], Wt, xb[l][d], mode, ba);
      else
        k_gat16<<<(Nd + 15) / 16, 256, 0, stream>>>(rowptr_t[t], rows_t[t], aSp[t], sSs[t],
                                                    aDp[t], sDs[t], xhp[t], Wt, xb[l][d], Nd, mode, ba);
    }
    xcur[0] = xb[l][0]; xcur[1] = xb[l][1]; xcur[2] = xb[l][2];
  }
  k_final<<<((int)SZ_U + 255) / 256, 256, 0, stream>>>(x0[0], xb[0][0], xb[1][0], (float*)d_out, (int)SZ_U);
  k_final<<<((int)SZ_A + 255) / 256, 256, 0, stream>>>(x0[1], xb[0][1], xb[1][1], (float*)d_out + SZ_U, (int)SZ_A);
}

// Round 4
// 2099.083 us; speedup vs baseline: 1.0160x; 1.0160x over previous
//
#include <hip/hip_runtime.h>
#include <hip/hip_fp16.h>

// MAHGN: 2-layer hetero GAT, fp32 math / fp16 message payload.
// Round 9: latency-bound gather attacked structurally:
//  - merged per-dst-type gather kernel (user: t1,t2,t3,t7; article: t0,t5):
//    out written ONCE with fused bias+leaky (no RMW traffic, no k_act).
//  - per-wave epilogue through wave-private LDS slice, NO __syncthreads:
//    waves retire independently (R5-style turnover; no parking in the
//    degree-imbalance tail).
//  - 2-edge unrolled loop, clamped branch-free depth-2 prefetch: 4 scattered
//    VMEM in flight per group (R8 had 2).

static constexpr int kNUser = 200000;
static constexpr int kNArt  = 100000;
static constexpr int kNCat  = 500;
static constexpr size_t SZ_U = (size_t)kNUser * 64;
static constexpr size_t SZ_A = (size_t)kNArt * 64;
static constexpr size_t SZ_C = (size_t)kNCat * 64;
static constexpr size_t SZ_X = SZ_U + SZ_A + SZ_C;
static constexpr int CHUNK = 4096;

__device__ __forceinline__ uint32_t packh2(float a, float b) {
  __half2 t = __floats2half2_rn(a, b);
  return *reinterpret_cast<uint32_t*>(&t);
}
__device__ __forceinline__ float2 unpackh2(uint32_t u) {
  __half2 t = *reinterpret_cast<__half2*>(&u);
  return __half22float2(t);
}

// ---------------- fold: vs[k,h] = sum_c W[k][h*16+c]*att[h*16+c] ----------------
__global__ void k_fold(const float* __restrict__ Wsrc, const float* __restrict__ Wdst,
                       const float* __restrict__ attS, const float* __restrict__ attD,
                       float* __restrict__ fold)
{
  int lt = blockIdx.x;
  int tid = threadIdx.x;
  int k = tid >> 2, h = tid & 3;
  const float* Ws = Wsrc + (size_t)lt * 4096;
  const float* Wd = Wdst + (size_t)lt * 4096;
  const float* aS = attS + (size_t)lt * 64;
  const float* aD = attD + (size_t)lt * 64;
  float s = 0.f, d = 0.f;
  #pragma unroll
  for (int c = 0; c < 16; ++c) {
    s += Ws[k * 64 + h * 16 + c] * aS[h * 16 + c];
    d += Wd[k * 64 + h * 16 + c] * aD[h * 16 + c];
  }
  fold[((size_t)lt * 2 + 0) * 256 + tid] = s;
  fold[((size_t)lt * 2 + 1) * 256 + tid] = d;
}

// summed bias per (layer, dst-type): user {1,2,3,7}, article {0,5}, category {4,6}
__global__ void k_bsum(const float* __restrict__ bias, float* __restrict__ bact) {
  int l = blockIdx.x;
  int tid = threadIdx.x;            // 192
  int d = tid >> 6, c = tid & 63;
  const float* b = bias + (size_t)l * 512;
  float v;
  if (d == 0)      v = b[64 + c] + b[128 + c] + b[192 + c] + b[448 + c];
  else if (d == 1) v = b[c] + b[320 + c];
  else             v = b[256 + c] + b[384 + c];
  bact[((size_t)l * 3 + d) * 64 + c] = v;
}

// ---------------- k_attn: per node type, all folded GEMVs + fp16 cast ----------------
template <int NV>
__global__ __launch_bounds__(256) void k_attn(const float* __restrict__ x,
    uint4* __restrict__ xh, const float* __restrict__ fold,
    int4 sa, int4 sb, float* __restrict__ aout, int Ns)
{
  __shared__ float sV[NV * 256];
  int tid = threadIdx.x;
  const int slots[8] = {sa.x, sa.y, sa.z, sa.w, sb.x, sb.y, sb.z, sb.w};
  #pragma unroll
  for (int v = 0; v < NV; ++v)
    sV[v * 256 + tid] = fold[(size_t)slots[v] * 256 + tid];
  __syncthreads();
  int n = blockIdx.x * 256 + tid;
  if (n >= Ns) return;
  const float4* xp = (const float4*)(x + (size_t)n * 64);
  float4 xr[16];
  #pragma unroll
  for (int q = 0; q < 16; ++q) xr[q] = xp[q];
  uint4* dst = xh + (size_t)n * 8;
  #pragma unroll
  for (int q = 0; q < 8; ++q) {
    uint4 u;
    u.x = packh2(xr[2 * q].x, xr[2 * q].y);
    u.y = packh2(xr[2 * q].z, xr[2 * q].w);
    u.z = packh2(xr[2 * q + 1].x, xr[2 * q + 1].y);
    u.w = packh2(xr[2 * q + 1].z, xr[2 * q + 1].w);
    dst[q] = u;
  }
  #pragma unroll
  for (int v = 0; v < NV; ++v) {
    float a0 = 0.f, a1 = 0.f, a2 = 0.f, a3 = 0.f;
    #pragma unroll
    for (int q = 0; q < 16; ++q) {
      const float* xf = &xr[q].x;
      #pragma unroll
      for (int j = 0; j < 4; ++j) {
        int k = q * 4 + j;
        float4 vv = *(const float4*)&sV[v * 256 + k * 4];
        float xk = xf[j];
        a0 += xk * vv.x; a1 += xk * vv.y; a2 += xk * vv.z; a3 += xk * vv.w;
      }
    }
    *(float4*)(aout + (size_t)n * (NV * 4) + v * 4) = make_float4(a0, a1, a2, a3);
  }
}

// ---------------- CSR build: two-level LDS multisplit (unchanged) ----------------

__global__ __launch_bounds__(256) void k_bhist(const int* __restrict__ col, int E,
    int nblk, int nbin, int shift, int* __restrict__ bh)
{
  __shared__ int h[1024];
  int tid = threadIdx.x;
  for (int j = tid; j < nbin; j += 256) h[j] = 0;
  __syncthreads();
  int b = blockIdx.x;
  int lo = b * CHUNK, hi = min(E, lo + CHUNK);
  for (int i = lo + tid; i < hi; i += 256) atomicAdd(&h[col[i] >> shift], 1);
  __syncthreads();
  for (int j = tid; j < nbin; j += 256) bh[j * nblk + b] = h[j];   // bin-major
}

__global__ __launch_bounds__(256) void k_s1(const int* __restrict__ a,
    int* __restrict__ bsum, int n)
{
  __shared__ int tmp[256];
  int t = threadIdx.x;
  int base = blockIdx.x * 4096 + t * 16;
  int s = 0;
  #pragma unroll
  for (int i = 0; i < 16; ++i) { int idx = base + i; if (idx < n) s += a[idx]; }
  tmp[t] = s;
  __syncthreads();
  for (int off = 128; off > 0; off >>= 1) {
    if (t < off) tmp[t] += tmp[t + off];
    __syncthreads();
  }
  if (t == 0) bsum[blockIdx.x] = tmp[0];
}

__global__ __launch_bounds__(1024) void k_s2(int* __restrict__ bsum, int nb) {
  __shared__ int tmp[1024];
  int t = threadIdx.x;
  int v = (t < nb) ? bsum[t] : 0;
  tmp[t] = v;
  __syncthreads();
  for (int off = 1; off < 1024; off <<= 1) {
    int u = (t >= off) ? tmp[t - off] : 0;
    __syncthreads();
    tmp[t] += u;
    __syncthreads();
  }
  if (t < nb) bsum[t] = tmp[t] - v;   // exclusive
}

__global__ __launch_bounds__(256) void k_s3(int* __restrict__ a,
    const int* __restrict__ bsum, int n)
{
  __shared__ int tw[256];
  int t = threadIdx.x;
  int base = blockIdx.x * 4096 + t * 16;
  int v[16];
  int s = 0;
  #pragma unroll
  for (int i = 0; i < 16; ++i) { int idx = base + i; v[i] = (idx < n) ? a[idx] : 0; s += v[i]; }
  tw[t] = s;
  __syncthreads();
  for (int off = 1; off < 256; off <<= 1) {
    int u = (t >= off) ? tw[t - off] : 0;
    __syncthreads();
    tw[t] += u;
    __syncthreads();
  }
  int excl = bsum[blockIdx.x] + tw[t] - s;
  #pragma unroll
  for (int i = 0; i < 16; ++i) {
    int idx = base + i;
    if (idx < n) { a[idx] = excl; excl += v[i]; }
  }
}

__global__ void k_binbase(const int* __restrict__ bh, int nblk, int nbin, int E,
                          int* __restrict__ binbase)
{
  int j = blockIdx.x * 256 + threadIdx.x;
  if (j < nbin) binbase[j] = bh[(size_t)j * nblk];
  if (j == nbin) binbase[nbin] = E;
}

__global__ __launch_bounds__(256) void k_bscat(const int* __restrict__ row,
    const int* __restrict__ col, int E, int nblk, int nbin, int shift,
    const int* __restrict__ bh,
    int* __restrict__ trow, int* __restrict__ tcol)
{
  __shared__ int cur[1024];
  int tid = threadIdx.x;
  int b = blockIdx.x;
  for (int j = tid; j < nbin; j += 256) cur[j] = bh[j * nblk + b];
  __syncthreads();
  int lo = b * CHUNK, hi = min(E, lo + CHUNK);
  for (int i = lo + tid; i < hi; i += 256) {
    int c = col[i];
    int p = atomicAdd(&cur[c >> shift], 1);
    trow[p] = row[i];
    if (tcol) tcol[p] = c;
  }
}

__global__ __launch_bounds__(256) void k_fine(const int* __restrict__ trow,
    const int* __restrict__ tcol, const int* __restrict__ binbase,
    int* __restrict__ rowptr, int* __restrict__ rows, int Nd, int nbin)
{
  __shared__ int h[256], sc[256], cur[256];
  int tid = threadIdx.x;
  int bin = blockIdx.x;
  int s = binbase[bin], e = binbase[bin + 1];
  h[tid] = 0;
  __syncthreads();
  for (int k = s + tid; k < e; k += 256) atomicAdd(&h[tcol[k] & 255], 1);
  __syncthreads();
  int own = h[tid];
  sc[tid] = own;
  __syncthreads();
  for (int off = 1; off < 256; off <<= 1) {
    int t = (tid >= off) ? sc[tid - off] : 0;
    __syncthreads();
    sc[tid] += t;
    __syncthreads();
  }
  int excl = sc[tid] - own;
  int dst = bin * 256 + tid;
  if (dst < Nd) rowptr[dst] = s + excl;
  cur[tid] = s + excl;
  if (bin == 0 && tid == 0) rowptr[Nd] = binbase[nbin];
  __syncthreads();
  for (int k = s + tid; k < e; k += 256) {
    int p = atomicAdd(&cur[tcol[k] & 255], 1);
    rows[p] = trow[k];
  }
}

__global__ void k_rp(const int* __restrict__ binbase, int* __restrict__ rowptr, int Nd) {
  int i = blockIdx.x * 256 + threadIdx.x;
  if (i <= Nd) rowptr[i] = binbase[i];
}

// ---------------- merged gather: all edge types of one dst type ----------------
// Per-type pointer bundle (kernel arg by value).
struct GArgs {
  const int* rowptr[4];
  const int* rows[4];
  const float* aS[4];
  const float* aD[4];
  const uint32_t* xh[4];
  const float* W[4];
  int sS[4];
  int sD[4];
};

// 256 thr = 16 groups x 16 lanes; group handles dst n = blockIdx*16 + grp.
// Lane l owns dims 4l..4l+3; computes all 4 head exps from a broadcast a_s
// float4. Epilogue is WAVE-LOCAL (sAgg slice per group, wave_barrier only):
// no __syncthreads anywhere -> waves retire independently.
template <int NT>
__global__ __launch_bounds__(256) void k_gatM(GArgs A, float* __restrict__ out,
                                              int Nd, const float* __restrict__ bact)
{
  __shared__ float sAgg[16][4][68];   // 17.4 KB: [group][head][dim(+pad)]
  int tid = threadIdx.x;
  int grp = tid >> 4, l = tid & 15;
  int n = blockIdx.x * 16 + grp;
  bool ok = n < Nd;
  int c4 = l, hh = l >> 2;
  float4 outacc = make_float4(0.f, 0.f, 0.f, 0.f);

  #pragma unroll
  for (int t = 0; t < NT; ++t) {
    const int* __restrict__ rows = A.rows[t];
    const float* __restrict__ aS = A.aS[t];
    const uint32_t* __restrict__ xh = A.xh[t];
    int sS = A.sS[t];
    float acc[4][4] = {{0.f,0.f,0.f,0.f},{0.f,0.f,0.f,0.f},
                       {0.f,0.f,0.f,0.f},{0.f,0.f,0.f,0.f}};
    float den[4] = {0.f, 0.f, 0.f, 0.f};
    if (ok) {
      float4 ad4 = *(const float4*)(A.aD[t] + (size_t)n * A.sD[t]);
      int start = A.rowptr[t][n], end = A.rowptr[t][n + 1];
      if (start < end) {
        int e1 = end - 1;
        int k = start;
        int ra = rows[k];
        int rb = rows[min(k + 1, e1)];
        float4 asA = *(const float4*)(aS + (size_t)ra * sS);
        float4 asB = *(const float4*)(aS + (size_t)rb * sS);
        uint2 xrA = *(const uint2*)(xh + (size_t)ra * 32 + l * 2);
        uint2 xrB = *(const uint2*)(xh + (size_t)rb * 32 + l * 2);
        for (; k < end; k += 2) {
          // clamped branch-free prefetch, depth 2 (4 scattered VMEM in flight)
          int rc = rows[min(k + 2, e1)];
          int rd = rows[min(k + 3, e1)];
          float4 asC = *(const float4*)(aS + (size_t)rc * sS);
          float4 asD = *(const float4*)(aS + (size_t)rd * sS);
          uint2 xrC = *(const uint2*)(xh + (size_t)rc * 32 + l * 2);
          uint2 xrD = *(const uint2*)(xh + (size_t)rd * 32 + l * 2);
          {
            float2 x01 = unpackh2(xrA.x), x23 = unpackh2(xrA.y);
            const float* asf = &asA.x; const float* adf = &ad4.x;
            #pragma unroll
            for (int m = 0; m < 4; ++m) {
              float v = asf[m] + adf[m];
              v = v >= 0.f ? v : 0.2f * v;
              float p = __expf(v);   // logits O(1): plain exp is numerically safe
              den[m] += p;
              acc[m][0] += p * x01.x; acc[m][1] += p * x01.y;
              acc[m][2] += p * x23.x; acc[m][3] += p * x23.y;
            }
          }
          if (k + 1 < end) {
            float2 x01 = unpackh2(xrB.x), x23 = unpackh2(xrB.y);
            const float* asf = &asB.x; const float* adf = &ad4.x;
            #pragma unroll
            for (int m = 0; m < 4; ++m) {
              float v = asf[m] + adf[m];
              v = v >= 0.f ? v : 0.2f * v;
              float p = __expf(v);
              den[m] += p;
              acc[m][0] += p * x01.x; acc[m][1] += p * x01.y;
              acc[m][2] += p * x23.x; acc[m][3] += p * x23.y;
            }
          }
          asA = asC; asB = asD; xrA = xrC; xrB = xrD;
        }
      }
    }
    // normalized aggregate -> wave-private LDS slice (transpose for epilogue)
    #pragma unroll
    for (int m = 0; m < 4; ++m) {
      float inv = 1.f / (den[m] + 1e-16f);
      *(float4*)&sAgg[grp][m][l * 4] = make_float4(
          acc[m][0] * inv, acc[m][1] * inv, acc[m][2] * inv, acc[m][3] * inv);
    }
    __builtin_amdgcn_wave_barrier();   // wave-synchronous; lgkmcnt ordered by compiler
    // epilogue GEMM for this type: outacc[c] += sum_k agg[head(c)][k] * W[k][c]
    const float* __restrict__ W = A.W[t];
    float4 r = outacc;
    #pragma unroll 2
    for (int k4 = 0; k4 < 16; ++k4) {
      float4 a4 = *(const float4*)&sAgg[grp][hh][k4 * 4];
      float4 w0 = *(const float4*)(W + (k4 * 4 + 0) * 64 + c4 * 4);
      float4 w1 = *(const float4*)(W + (k4 * 4 + 1) * 64 + c4 * 4);
      float4 w2 = *(const float4*)(W + (k4 * 4 + 2) * 64 + c4 * 4);
      float4 w3 = *(const float4*)(W + (k4 * 4 + 3) * 64 + c4 * 4);
      r.x += a4.x * w0.x + a4.y * w1.x + a4.z * w2.x + a4.w * w3.x;
      r.y += a4.x * w0.y + a4.y * w1.y + a4.z * w2.y + a4.w * w3.y;
      r.z += a4.x * w0.z + a4.y * w1.z + a4.z * w2.z + a4.w * w3.z;
      r.w += a4.x * w0.w + a4.y * w1.w + a4.z * w2.w + a4.w * w3.w;
    }
    outacc = r;
    __builtin_amdgcn_wave_barrier();   // WAR: next type rewrites sAgg
  }
  if (ok) {
    float4 bb = ((const float4*)bact)[c4];
    float4 pv = outacc;
    pv.x += bb.x; pv.y += bb.y; pv.z += bb.z; pv.w += bb.w;
    pv.x = pv.x >= 0.f ? pv.x : 0.01f * pv.x;
    pv.y = pv.y >= 0.f ? pv.y : 0.01f * pv.y;
    pv.z = pv.z >= 0.f ? pv.z : 0.01f * pv.z;
    pv.w = pv.w >= 0.f ? pv.w : 0.01f * pv.w;
    *((float4*)(out + (size_t)n * 64) + c4) = pv;
  }
}

// big-degree path: one block per dst (category, Nd=500), 16 subgroups stride edges.
// mode: 1 = first (plain write), 2 = last (RMW + bias + leaky)
__global__ __launch_bounds__(256) void k_gatB(const int* __restrict__ rowptr,
    const int* __restrict__ rows, const float* __restrict__ aS, int sS,
    const float* __restrict__ aD, int sD, const uint32_t* __restrict__ xh,
    const float* __restrict__ W, float* __restrict__ out,
    int mode, const float* __restrict__ bact)
{
  __shared__ float sAgg[16][4][68];
  __shared__ float sDen[16][4];
  __shared__ float sRes[256];
  int n = blockIdx.x;
  int tid = threadIdx.x;
  int g = tid >> 4, l = tid & 15;
  float4 ad4 = *(const float4*)(aD + (size_t)n * sD);
  int start = rowptr[n], end = rowptr[n + 1];
  float acc[4][4] = {{0.f,0.f,0.f,0.f},{0.f,0.f,0.f,0.f},{0.f,0.f,0.f,0.f},{0.f,0.f,0.f,0.f}};
  float den[4] = {0.f, 0.f, 0.f, 0.f};
  int k = start + g;
  float4 asN = make_float4(0.f, 0.f, 0.f, 0.f);
  uint2 xrN = make_uint2(0, 0);
  if (k < end) {
    int r0 = rows[k];
    asN = *(const float4*)(aS + (size_t)r0 * sS);
    xrN = *(const uint2*)(xh + (size_t)r0 * 32 + l * 2);
  }
  for (; k < end; k += 16) {
    float4 as4 = asN;
    uint2 xr = xrN;
    if (k + 16 < end) {
      int r2 = rows[k + 16];
      asN = *(const float4*)(aS + (size_t)r2 * sS);
      xrN = *(const uint2*)(xh + (size_t)r2 * 32 + l * 2);
    }
    float2 x01 = unpackh2(xr.x);
    float2 x23 = unpackh2(xr.y);
    const float* asf = &as4.x;
    const float* adf = &ad4.x;
    #pragma unroll
    for (int m = 0; m < 4; ++m) {
      float v = asf[m] + adf[m];
      v = v >= 0.f ? v : 0.2f * v;
      float p = __expf(v);
      den[m] += p;
      acc[m][0] += p * x01.x; acc[m][1] += p * x01.y;
      acc[m][2] += p * x23.x; acc[m][3] += p * x23.y;
    }
  }
  #pragma unroll
  for (int m = 0; m < 4; ++m)
    *(float4*)&sAgg[g][m][l * 4] =
        make_float4(acc[m][0], acc[m][1], acc[m][2], acc[m][3]);
  if (l == 0) {
    sDen[g][0] = den[0]; sDen[g][1] = den[1]; sDen[g][2] = den[2]; sDen[g][3] = den[3];
  }
  __syncthreads();
  int hh = tid >> 6, dim = tid & 63;
  float A = 0.f;
  #pragma unroll
  for (int gg = 0; gg < 16; ++gg) A += sAgg[gg][hh][dim];
  float D = 0.f;
  #pragma unroll
  for (int gg = 0; gg < 16; ++gg) D += sDen[gg][hh];
  sRes[tid] = A / (D + 1e-16f);     // [head*64 + dim]
  __syncthreads();
  if (tid < 64) {
    int hc = tid >> 4;
    float r = 0.f;
    #pragma unroll 8
    for (int k2 = 0; k2 < 64; ++k2) r += sRes[hc * 64 + k2] * W[k2 * 64 + tid];
    size_t idx = (size_t)n * 64 + tid;
    float v = (mode == 1) ? r : out[idx] + r;
    if (mode == 2) {
      v += bact[tid];
      v = v >= 0.f ? v : 0.01f * v;
    }
    out[idx] = v;
  }
}

// ---------------- epilogue ----------------

__global__ void k_final(const float* __restrict__ x0, const float* __restrict__ x1,
                        const float* __restrict__ x2, float* __restrict__ out, int n)
{
  int i = blockIdx.x * blockDim.x + threadIdx.x;
  if (i < n) out[i] = (x0[i] + x1[i] + x2[i]) * (1.f / 3.f);
}

// ---------------- launch ----------------

extern "C" void kernel_launch(void* const* d_in, const int* in_sizes, int n_in,
                              void* d_out, int out_size, void* d_ws, size_t ws_size,
                              hipStream_t stream)
{
  static const int ECNT[8] = {1000000, 1000000, 500000, 500000, 100000, 100000, 500000, 500000};
  static const int EDST[8] = {1, 0, 0, 0, 2, 1, 2, 0};
  const int NSZ[3] = {kNUser, kNArt, kNCat};

  const float* x0[3] = {(const float*)d_in[0], (const float*)d_in[1], (const float*)d_in[2]};
  const float* Wsrc = (const float*)d_in[3];
  const float* Wdst = (const float*)d_in[4];
  const float* attS = (const float*)d_in[5];
  const float* attD = (const float*)d_in[6];
  const float* bias = (const float*)d_in[7];
  const int* ei[8];
  for (int t = 0; t < 8; ++t) ei[t] = (const int*)d_in[8 + t];

  float* ws = (float*)d_ws;
  size_t off = 0;
  auto alloc = [&](size_t nelem) { float* p = ws + off; off += nelem; return p; };
  float* xb0 = alloc(SZ_X);
  float* xb1 = alloc(SZ_X);
  float* xhf = alloc(SZ_X / 2);            // fp16 copy of current x
  float* aU  = alloc((size_t)kNUser * 32); // 8 slots x 4 heads
  float* aA  = alloc((size_t)kNArt * 16);  // 4 slots
  float* aC  = alloc((size_t)kNCat * 16);  // 4 slots
  float* fold = alloc(16 * 2 * 256);
  float* bact = alloc(2 * 3 * 64);
  int* rowptrA = (int*)alloc(1001008);
  int* rowsA   = (int*)alloc(4200000);
  int* tmp_row = (int*)alloc(1000000);
  int* tmp_col = (int*)alloc(1000000);
  int* blockhist = (int*)alloc(200704);
  int* binbase   = (int*)alloc(1032);
  int* bsum      = (int*)alloc(1024);

  uint32_t* xh32 = (uint32_t*)xhf;
  uint32_t* xh_u = xh32;
  uint32_t* xh_a = xh32 + (size_t)kNUser * 32;
  uint32_t* xh_c = xh_a + (size_t)kNArt * 32;

  int* rowptr_t[8]; int* rows_t[8];
  {
    size_t ro = 0, eo = 0;
    for (int t = 0; t < 8; ++t) {
      int Nd = NSZ[EDST[t]];
      rowptr_t[t] = rowptrA + ro; ro += (size_t)Nd + 1;
      rows_t[t]   = rowsA + eo;   eo += (size_t)ECNT[t];
    }
  }

  // per-type a_s/a_d pointers into interleaved per-node-type tables
  // user slots: [t0s,t2s,t3s,t6s, t1d,t2d,t3d,t7d]; art: [t1s,t4s, t0d,t5d]; cat: [t5s,t7s, t4d,t6d]
  float* aSp[8] = {aU + 0, aA + 0, aU + 4, aU + 8, aA + 4, aC + 0, aU + 12, aC + 4};
  int    sSs[8] = {32, 16, 32, 32, 16, 16, 32, 16};
  float* aDp[8] = {aA + 8, aU + 16, aU + 20, aU + 24, aC + 8, aA + 12, aC + 12, aU + 28};
  int    sDs[8] = {16, 32, 32, 32, 16, 16, 16, 32};
  const uint32_t* xhp[8] = {xh_u, xh_a, xh_u, xh_u, xh_a, xh_c, xh_u, xh_c};

  // ---- fold attention vectors + summed biases ----
  k_fold<<<16, 256, 0, stream>>>(Wsrc, Wdst, attS, attD, fold);
  k_bsum<<<2, 192, 0, stream>>>(bias, bact);

  // ---- CSR build: two-level LDS multisplit (no global atomics) ----
  for (int t = 0; t < 8; ++t) {
    int Nd = NSZ[EDST[t]], E = ECNT[t];
    const int* row = ei[t];
    const int* col = ei[t] + E;
    int shift = (Nd <= 1024) ? 0 : 8;
    int nbin = ((Nd - 1) >> shift) + 1;
    int nblk = (E + CHUNK - 1) / CHUNK;
    int n = nbin * nblk;
    int nb2 = (n + 4095) / 4096;
    k_bhist<<<nblk, 256, 0, stream>>>(col, E, nblk, nbin, shift, blockhist);
    k_s1<<<nb2, 256, 0, stream>>>(blockhist, bsum, n);
    k_s2<<<1, 1024, 0, stream>>>(bsum, nb2);
    k_s3<<<nb2, 256, 0, stream>>>(blockhist, bsum, n);
    k_binbase<<<(nbin + 256) / 256, 256, 0, stream>>>(blockhist, nblk, nbin, E, binbase);
    if (shift == 0) {
      k_bscat<<<nblk, 256, 0, stream>>>(row, col, E, nblk, nbin, 0,
                                        blockhist, rows_t[t], nullptr);
      k_rp<<<(Nd + 256) / 256, 256, 0, stream>>>(binbase, rowptr_t[t], Nd);
    } else {
      k_bscat<<<nblk, 256, 0, stream>>>(row, col, E, nblk, nbin, 8,
                                        blockhist, tmp_row, tmp_col);
      k_fine<<<nbin, 256, 0, stream>>>(tmp_row, tmp_col, binbase,
                                       rowptr_t[t], rows_t[t], Nd, nbin);
    }
  }

  float* xb[2][3] = {{xb0, xb0 + SZ_U, xb0 + SZ_U + SZ_A},
                     {xb1, xb1 + SZ_U, xb1 + SZ_U + SZ_A}};
  const float* xcur[3] = {x0[0], x0[1], x0[2]};
  for (int l = 0; l < 2; ++l) {
    // fold-slot id for (t, sd): ((l*8+t)*2 + sd)
    auto F = [&](int t, int sd) { return (l * 8 + t) * 2 + sd; };
    int4 ua = make_int4(F(0, 0), F(2, 0), F(3, 0), F(6, 0));
    int4 ub = make_int4(F(1, 1), F(2, 1), F(3, 1), F(7, 1));
    int4 aa = make_int4(F(1, 0), F(4, 0), F(0, 1), F(5, 1));
    int4 ca = make_int4(F(5, 0), F(7, 0), F(4, 1), F(6, 1));
    k_attn<8><<<(kNUser + 255) / 256, 256, 0, stream>>>(xcur[0], (uint4*)xh_u, fold, ua, ub, aU, kNUser);
    k_attn<4><<<(kNArt + 255) / 256, 256, 0, stream>>>(xcur[1], (uint4*)xh_a, fold, aa, aa, aA, kNArt);
    k_attn<4><<<(kNCat + 255) / 256, 256, 0, stream>>>(xcur[2], (uint4*)xh_c, fold, ca, ca, aC, kNCat);

    // merged gathers: user {t1,t2,t3,t7}, article {t0,t5}; category via gatB.
    auto mkargs = [&](const int* tl, int nt) {
      GArgs A{};
      for (int i = 0; i < 4; ++i) {
        int t = tl[i < nt ? i : 0];
        A.rowptr[i] = rowptr_t[t];
        A.rows[i]   = rows_t[t];
        A.aS[i]     = aSp[t];
        A.aD[i]     = aDp[t];
        A.xh[i]     = xhp[t];
        A.W[i]      = Wsrc + (size_t)(l * 8 + t) * 4096;
        A.sS[i]     = sSs[t];
        A.sD[i]     = sDs[t];
      }
      return A;
    };
    static const int UL[4] = {1, 2, 3, 7};
    static const int AL[2] = {0, 5};
    GArgs AU_ = mkargs(UL, 4);
    GArgs AA_ = mkargs(AL, 2);
    k_gatM<4><<<(kNUser + 15) / 16, 256, 0, stream>>>(AU_, xb[l][0], kNUser,
                                                      bact + ((size_t)l * 3 + 0) * 64);
    k_gatM<2><<<(kNArt + 15) / 16, 256, 0, stream>>>(AA_, xb[l][1], kNArt,
                                                     bact + ((size_t)l * 3 + 1) * 64);
    // category: t4 first (write), t6 last (RMW + bias + leaky)
    k_gatB<<<kNCat, 256, 0, stream>>>(rowptr_t[4], rows_t[4], aSp[4], sSs[4],
                                      aDp[4], sDs[4], xhp[4],
                                      Wsrc + (size_t)(l * 8 + 4) * 4096,
                                      xb[l][2], 1, nullptr);
    k_gatB<<<kNCat, 256, 0, stream>>>(rowptr_t[6], rows_t[6], aSp[6], sSs[6],
                                      aDp[6], sDs[6], xhp[6],
                                      Wsrc + (size_t)(l * 8 + 6) * 4096,
                                      xb[l][2], 2, bact + ((size_t)l * 3 + 2) * 64);
    xcur[0] = xb[l][0]; xcur[1] = xb[l][1]; xcur[2] = xb[l][2];
  }
  k_final<<<((int)SZ_U + 255) / 256, 256, 0, stream>>>(x0[0], xb[0][0], xb[1][0], (float*)d_out, (int)SZ_U);
  k_final<<<((int)SZ_A + 255) / 256, 256, 0, stream>>>(x0[1], xb[0][1], xb[1][1], (float*)d_out + SZ_U, (int)SZ_A);
}

// Round 5
// 1633.858 us; speedup vs baseline: 1.3053x; 1.2847x over previous
//
#include <hip/hip_runtime.h>
#include <hip/hip_fp16.h>

// MAHGN: 2-layer hetero GAT.
// Round 10: recombination of proven parts. R6-R9's deferred-W aggregation is
// VALU-issue-bound (4x per-head redundancy, ~44 instr/edge/lane vs R5's ~15)
// -> revert to R5's hs-materialized gather (measured 65us/1M @3.5TB/s), but:
//  - hs stored fp16 (half transform write + half gather read bytes; 25MB
//    user table ~ L2-resident)
//  - a_s/a_d from folded GEMVs (k_attn; no k_ad), laid out as per-slot
//    planes (stride 4) so scattered a_s reads waste no cache line
//  - bias+leaky fused into last gather per dst (modes; no k_act, no memsets)

static constexpr int kNUser = 200000;
static constexpr int kNArt  = 100000;
static constexpr int kNCat  = 500;
static constexpr size_t SZ_U = (size_t)kNUser * 64;
static constexpr size_t SZ_A = (size_t)kNArt * 64;
static constexpr size_t SZ_C = (size_t)kNCat * 64;
static constexpr size_t SZ_X = SZ_U + SZ_A + SZ_C;
static constexpr int CHUNK = 4096;

__device__ __forceinline__ uint32_t packh2(float a, float b) {
  __half2 t = __floats2half2_rn(a, b);
  return *reinterpret_cast<uint32_t*>(&t);
}
__device__ __forceinline__ float2 unpackh2(uint32_t u) {
  __half2 t = *reinterpret_cast<__half2*>(&u);
  return __half22float2(t);
}

// ---------------- fold: vs[k,h] = sum_c W[k][h*16+c]*att[h*16+c] ----------------
__global__ void k_fold(const float* __restrict__ Wsrc, const float* __restrict__ Wdst,
                       const float* __restrict__ attS, const float* __restrict__ attD,
                       float* __restrict__ fold)
{
  int lt = blockIdx.x;
  int tid = threadIdx.x;
  int k = tid >> 2, h = tid & 3;
  const float* Ws = Wsrc + (size_t)lt * 4096;
  const float* Wd = Wdst + (size_t)lt * 4096;
  const float* aS = attS + (size_t)lt * 64;
  const float* aD = attD + (size_t)lt * 64;
  float s = 0.f, d = 0.f;
  #pragma unroll
  for (int c = 0; c < 16; ++c) {
    s += Ws[k * 64 + h * 16 + c] * aS[h * 16 + c];
    d += Wd[k * 64 + h * 16 + c] * aD[h * 16 + c];
  }
  fold[((size_t)lt * 2 + 0) * 256 + tid] = s;
  fold[((size_t)lt * 2 + 1) * 256 + tid] = d;
}

// summed bias per (layer, dst-type): user {1,2,3,7}, article {0,5}, category {4,6}
__global__ void k_bsum(const float* __restrict__ bias, float* __restrict__ bact) {
  int l = blockIdx.x;
  int tid = threadIdx.x;            // 192
  int d = tid >> 6, c = tid & 63;
  const float* b = bias + (size_t)l * 512;
  float v;
  if (d == 0)      v = b[64 + c] + b[128 + c] + b[192 + c] + b[448 + c];
  else if (d == 1) v = b[c] + b[320 + c];
  else             v = b[256 + c] + b[384 + c];
  bact[((size_t)l * 3 + d) * 64 + c] = v;
}

// ---------------- k_attn: per node type, all folded GEMVs (plane outputs) ----------------
template <int NV>
__global__ __launch_bounds__(256) void k_attn(const float* __restrict__ x,
    const float* __restrict__ fold, int4 sa, int4 sb,
    float* __restrict__ aout, int Ns)
{
  __shared__ float sV[NV * 256];
  int tid = threadIdx.x;
  const int slots[8] = {sa.x, sa.y, sa.z, sa.w, sb.x, sb.y, sb.z, sb.w};
  #pragma unroll
  for (int v = 0; v < NV; ++v)
    sV[v * 256 + tid] = fold[(size_t)slots[v] * 256 + tid];
  __syncthreads();
  int n = blockIdx.x * 256 + tid;
  if (n >= Ns) return;
  const float4* xp = (const float4*)(x + (size_t)n * 64);
  float4 xr[16];
  #pragma unroll
  for (int q = 0; q < 16; ++q) xr[q] = xp[q];
  #pragma unroll
  for (int v = 0; v < NV; ++v) {
    float a0 = 0.f, a1 = 0.f, a2 = 0.f, a3 = 0.f;
    #pragma unroll
    for (int q = 0; q < 16; ++q) {
      const float* xf = &xr[q].x;
      #pragma unroll
      for (int j = 0; j < 4; ++j) {
        int k = q * 4 + j;
        float4 vv = *(const float4*)&sV[v * 256 + k * 4];
        float xk = xf[j];
        a0 += xk * vv.x; a1 += xk * vv.y; a2 += xk * vv.z; a3 += xk * vv.w;
      }
    }
    // per-slot plane: [v][Ns][4]
    *(float4*)(aout + (size_t)v * Ns * 4 + (size_t)n * 4) = make_float4(a0, a1, a2, a3);
  }
}

// ---------------- transform: hs16 = fp16(x @ W), R5-proven tile ----------------
__global__ __launch_bounds__(256, 4) void k_trans(const float* __restrict__ x,
    const float* __restrict__ W, uint32_t* __restrict__ hs16, int Ns)
{
  __shared__ float sXt[64 * 68];
  __shared__ float sW[64 * 64];
  int tid = threadIdx.x;
  int r0 = blockIdx.x * 64;
  {
    const float4* w4 = (const float4*)W;
    float4* s4 = (float4*)sW;
    #pragma unroll
    for (int i = 0; i < 4; ++i) s4[tid + 256 * i] = w4[tid + 256 * i];
  }
  {
    int r = tid >> 4, kq = tid & 15;
    #pragma unroll
    for (int rg = 0; rg < 4; ++rg) {
      int row = r0 + rg * 16 + r;
      float4 xv = make_float4(0.f, 0.f, 0.f, 0.f);
      if (row < Ns) xv = *(const float4*)(x + (size_t)row * 64 + kq * 4);
      sXt[(kq * 4 + 0) * 68 + rg * 16 + r] = xv.x;
      sXt[(kq * 4 + 1) * 68 + rg * 16 + r] = xv.y;
      sXt[(kq * 4 + 2) * 68 + rg * 16 + r] = xv.z;
      sXt[(kq * 4 + 3) * 68 + rg * 16 + r] = xv.w;
    }
  }
  __syncthreads();

  int c4 = tid & 15, r4 = tid >> 4;
  float acc[4][4];
  #pragma unroll
  for (int i = 0; i < 4; ++i)
    #pragma unroll
    for (int j = 0; j < 4; ++j) acc[i][j] = 0.f;

  #pragma unroll 16
  for (int k = 0; k < 64; ++k) {
    float4 xv = *(const float4*)&sXt[k * 68 + r4 * 4];
    float4 wv = *(const float4*)&sW[k * 64 + c4 * 4];
    const float* xf = &xv.x;
    const float* wf = &wv.x;
    #pragma unroll
    for (int i = 0; i < 4; ++i)
      #pragma unroll
      for (int j = 0; j < 4; ++j) acc[i][j] += xf[i] * wf[j];
  }
  #pragma unroll
  for (int i = 0; i < 4; ++i) {
    int row = r0 + r4 * 4 + i;
    if (row < Ns) {
      uint2 u;
      u.x = packh2(acc[i][0], acc[i][1]);
      u.y = packh2(acc[i][2], acc[i][3]);
      *(uint2*)(hs16 + (size_t)row * 32 + c4 * 2) = u;
    }
  }
}

// ---------------- CSR build: two-level LDS multisplit (unchanged) ----------------

__global__ __launch_bounds__(256) void k_bhist(const int* __restrict__ col, int E,
    int nblk, int nbin, int shift, int* __restrict__ bh)
{
  __shared__ int h[1024];
  int tid = threadIdx.x;
  for (int j = tid; j < nbin; j += 256) h[j] = 0;
  __syncthreads();
  int b = blockIdx.x;
  int lo = b * CHUNK, hi = min(E, lo + CHUNK);
  for (int i = lo + tid; i < hi; i += 256) atomicAdd(&h[col[i] >> shift], 1);
  __syncthreads();
  for (int j = tid; j < nbin; j += 256) bh[j * nblk + b] = h[j];   // bin-major
}

__global__ __launch_bounds__(256) void k_s1(const int* __restrict__ a,
    int* __restrict__ bsum, int n)
{
  __shared__ int tmp[256];
  int t = threadIdx.x;
  int base = blockIdx.x * 4096 + t * 16;
  int s = 0;
  #pragma unroll
  for (int i = 0; i < 16; ++i) { int idx = base + i; if (idx < n) s += a[idx]; }
  tmp[t] = s;
  __syncthreads();
  for (int off = 128; off > 0; off >>= 1) {
    if (t < off) tmp[t] += tmp[t + off];
    __syncthreads();
  }
  if (t == 0) bsum[blockIdx.x] = tmp[0];
}

__global__ __launch_bounds__(1024) void k_s2(int* __restrict__ bsum, int nb) {
  __shared__ int tmp[1024];
  int t = threadIdx.x;
  int v = (t < nb) ? bsum[t] : 0;
  tmp[t] = v;
  __syncthreads();
  for (int off = 1; off < 1024; off <<= 1) {
    int u = (t >= off) ? tmp[t - off] : 0;
    __syncthreads();
    tmp[t] += u;
    __syncthreads();
  }
  if (t < nb) bsum[t] = tmp[t] - v;   // exclusive
}

__global__ __launch_bounds__(256) void k_s3(int* __restrict__ a,
    const int* __restrict__ bsum, int n)
{
  __shared__ int tw[256];
  int t = threadIdx.x;
  int base = blockIdx.x * 4096 + t * 16;
  int v[16];
  int s = 0;
  #pragma unroll
  for (int i = 0; i < 16; ++i) { int idx = base + i; v[i] = (idx < n) ? a[idx] : 0; s += v[i]; }
  tw[t] = s;
  __syncthreads();
  for (int off = 1; off < 256; off <<= 1) {
    int u = (t >= off) ? tw[t - off] : 0;
    __syncthreads();
    tw[t] += u;
    __syncthreads();
  }
  int excl = bsum[blockIdx.x] + tw[t] - s;
  #pragma unroll
  for (int i = 0; i < 16; ++i) {
    int idx = base + i;
    if (idx < n) { a[idx] = excl; excl += v[i]; }
  }
}

__global__ void k_binbase(const int* __restrict__ bh, int nblk, int nbin, int E,
                          int* __restrict__ binbase)
{
  int j = blockIdx.x * 256 + threadIdx.x;
  if (j < nbin) binbase[j] = bh[(size_t)j * nblk];
  if (j == nbin) binbase[nbin] = E;
}

__global__ __launch_bounds__(256) void k_bscat(const int* __restrict__ row,
    const int* __restrict__ col, int E, int nblk, int nbin, int shift,
    const int* __restrict__ bh,
    int* __restrict__ trow, int* __restrict__ tcol)
{
  __shared__ int cur[1024];
  int tid = threadIdx.x;
  int b = blockIdx.x;
  for (int j = tid; j < nbin; j += 256) cur[j] = bh[j * nblk + b];
  __syncthreads();
  int lo = b * CHUNK, hi = min(E, lo + CHUNK);
  for (int i = lo + tid; i < hi; i += 256) {
    int c = col[i];
    int p = atomicAdd(&cur[c >> shift], 1);
    trow[p] = row[i];
    if (tcol) tcol[p] = c;
  }
}

__global__ __launch_bounds__(256) void k_fine(const int* __restrict__ trow,
    const int* __restrict__ tcol, const int* __restrict__ binbase,
    int* __restrict__ rowptr, int* __restrict__ rows, int Nd, int nbin)
{
  __shared__ int h[256], sc[256], cur[256];
  int tid = threadIdx.x;
  int bin = blockIdx.x;
  int s = binbase[bin], e = binbase[bin + 1];
  h[tid] = 0;
  __syncthreads();
  for (int k = s + tid; k < e; k += 256) atomicAdd(&h[tcol[k] & 255], 1);
  __syncthreads();
  int own = h[tid];
  sc[tid] = own;
  __syncthreads();
  for (int off = 1; off < 256; off <<= 1) {
    int t = (tid >= off) ? sc[tid - off] : 0;
    __syncthreads();
    sc[tid] += t;
    __syncthreads();
  }
  int excl = sc[tid] - own;
  int dst = bin * 256 + tid;
  if (dst < Nd) rowptr[dst] = s + excl;
  cur[tid] = s + excl;
  if (bin == 0 && tid == 0) rowptr[Nd] = binbase[nbin];
  __syncthreads();
  for (int k = s + tid; k < e; k += 256) {
    int p = atomicAdd(&cur[tcol[k] & 255], 1);
    rows[p] = trow[k];
  }
}

__global__ void k_rp(const int* __restrict__ binbase, int* __restrict__ rowptr, int Nd) {
  int i = blockIdx.x * 256 + threadIdx.x;
  if (i <= Nd) rowptr[i] = binbase[i];
}

// ---------------- gather: R5-shape loop over fp16 hs ----------------
// 256 thr = 16 groups x 16 lanes; group g -> dst n = blockIdx*16+g.
// Lane l: head h=l>>2, dims 4l..4l+3 (hs is per-head transformed, so the
// lane's dims belong to its head). Per edge: 1 scalar a_s + 8B hs + 1 exp.
// mode: 0 = RMW, 1 = first (plain write), 2 = last (RMW + bias + leaky)
__global__ __launch_bounds__(256) void k_g16(const int* __restrict__ rowptr,
    const int* __restrict__ rows, const float* __restrict__ aS,
    const float* __restrict__ aD, const uint32_t* __restrict__ hs,
    float* __restrict__ out, int Nd, int mode, const float* __restrict__ bact)
{
  int tid = threadIdx.x;
  int g = tid >> 4, l = tid & 15, h = l >> 2;
  int n = blockIdx.x * 16 + g;
  if (n >= Nd) return;                 // no barriers in kernel
  float adh = aD[(size_t)n * 4 + h];
  int k = rowptr[n], end = rowptr[n + 1];
  float den = 0.f, ax = 0.f, ay = 0.f, az = 0.f, aw = 0.f;
  float aN = 0.f;
  uint2 xN = make_uint2(0, 0);
  if (k < end) {
    int r = rows[k];
    aN = aS[(size_t)r * 4 + h];
    xN = *(const uint2*)(hs + (size_t)r * 32 + l * 2);
  }
  for (; k < end; ++k) {
    float a = aN;
    uint2 x = xN;
    if (k + 1 < end) {                 // depth-1 prefetch
      int r = rows[k + 1];
      aN = aS[(size_t)r * 4 + h];
      xN = *(const uint2*)(hs + (size_t)r * 32 + l * 2);
    }
    float v = a + adh;
    v = v >= 0.f ? v : 0.2f * v;
    float p = __expf(v);   // logits O(1): plain exp is numerically safe
    float2 x01 = unpackh2(x.x);
    float2 x23 = unpackh2(x.y);
    den += p;
    ax += p * x01.x; ay += p * x01.y; az += p * x23.x; aw += p * x23.y;
  }
  float inv = 1.f / (den + 1e-16f);
  float4* op = (float4*)(out + (size_t)n * 64) + l;
  float4 pv;
  if (mode != 1) {
    pv = *op;
    pv.x += ax * inv; pv.y += ay * inv; pv.z += az * inv; pv.w += aw * inv;
  } else {
    pv = make_float4(ax * inv, ay * inv, az * inv, aw * inv);
  }
  if (mode == 2) {
    float4 bb = ((const float4*)bact)[l];
    pv.x += bb.x; pv.y += bb.y; pv.z += bb.z; pv.w += bb.w;
    pv.x = pv.x >= 0.f ? pv.x : 0.01f * pv.x;
    pv.y = pv.y >= 0.f ? pv.y : 0.01f * pv.y;
    pv.z = pv.z >= 0.f ? pv.z : 0.01f * pv.z;
    pv.w = pv.w >= 0.f ? pv.w : 0.01f * pv.w;
  }
  *op = pv;
}

// big-degree path: one block per dst (category), 16 subgroups stride edges.
__global__ __launch_bounds__(256) void k_gB(const int* __restrict__ rowptr,
    const int* __restrict__ rows, const float* __restrict__ aS,
    const float* __restrict__ aD, const uint32_t* __restrict__ hs,
    float* __restrict__ out, int mode, const float* __restrict__ bact)
{
  __shared__ float sacc[16][68];
  __shared__ float sden[16][4];
  int n = blockIdx.x;
  int tid = threadIdx.x;
  int sg = tid >> 4, l = tid & 15, h = l >> 2;
  float adh = aD[(size_t)n * 4 + h];
  int k = rowptr[n] + sg, end = rowptr[n + 1];
  float den = 0.f, ax = 0.f, ay = 0.f, az = 0.f, aw = 0.f;
  float aN = 0.f;
  uint2 xN = make_uint2(0, 0);
  if (k < end) {
    int r = rows[k];
    aN = aS[(size_t)r * 4 + h];
    xN = *(const uint2*)(hs + (size_t)r * 32 + l * 2);
  }
  for (; k < end; k += 16) {
    float a = aN;
    uint2 x = xN;
    if (k + 16 < end) {
      int r = rows[k + 16];
      aN = aS[(size_t)r * 4 + h];
      xN = *(const uint2*)(hs + (size_t)r * 32 + l * 2);
    }
    float v = a + adh;
    v = v >= 0.f ? v : 0.2f * v;
    float p = __expf(v);
    float2 x01 = unpackh2(x.x);
    float2 x23 = unpackh2(x.y);
    den += p;
    ax += p * x01.x; ay += p * x01.y; az += p * x23.x; aw += p * x23.y;
  }
  sacc[sg][l * 4 + 0] = ax;
  sacc[sg][l * 4 + 1] = ay;
  sacc[sg][l * 4 + 2] = az;
  sacc[sg][l * 4 + 3] = aw;
  if ((l & 3) == 0) sden[sg][h] = den;
  __syncthreads();
  if (tid < 64) {
    int hh = tid >> 4;
    float A = 0.f, D = 0.f;
    #pragma unroll
    for (int s2 = 0; s2 < 16; ++s2) { A += sacc[s2][tid]; D += sden[s2][hh]; }
    float r = A / (D + 1e-16f);
    size_t idx = (size_t)n * 64 + tid;
    float v = (mode == 1) ? r : out[idx] + r;
    if (mode == 2) {
      v += bact[tid];
      v = v >= 0.f ? v : 0.01f * v;
    }
    out[idx] = v;
  }
}

// ---------------- epilogue ----------------

__global__ void k_final(const float* __restrict__ x0, const float* __restrict__ x1,
                        const float* __restrict__ x2, float* __restrict__ out, int n)
{
  int i = blockIdx.x * blockDim.x + threadIdx.x;
  if (i < n) out[i] = (x0[i] + x1[i] + x2[i]) * (1.f / 3.f);
}

// ---------------- launch ----------------

extern "C" void kernel_launch(void* const* d_in, const int* in_sizes, int n_in,
                              void* d_out, int out_size, void* d_ws, size_t ws_size,
                              hipStream_t stream)
{
  static const int ECNT[8] = {1000000, 1000000, 500000, 500000, 100000, 100000, 500000, 500000};
  static const int ESRC[8] = {0, 1, 0, 0, 1, 2, 0, 2};   // 0=user 1=article 2=category
  static const int EDST[8] = {1, 0, 0, 0, 2, 1, 2, 0};
  // first/last gather per dst type: user first=t1 last=t7; art first=t0 last=t5; cat first=t4 last=t6
  static const int MODE[8] = {1, 1, 0, 0, 1, 2, 2, 2};
  const int NSZ[3] = {kNUser, kNArt, kNCat};

  const float* x0[3] = {(const float*)d_in[0], (const float*)d_in[1], (const float*)d_in[2]};
  const float* Wsrc = (const float*)d_in[3];
  const float* Wdst = (const float*)d_in[4];
  const float* attS = (const float*)d_in[5];
  const float* attD = (const float*)d_in[6];
  const float* bias = (const float*)d_in[7];
  const int* ei[8];
  for (int t = 0; t < 8; ++t) ei[t] = (const int*)d_in[8 + t];

  float* ws = (float*)d_ws;
  size_t off = 0;
  auto alloc = [&](size_t nelem) { float* p = ws + off; off += nelem; return p; };
  float* xb0 = alloc(SZ_X);
  float* xb1 = alloc(SZ_X);
  float* hsf = alloc((size_t)kNUser * 32);   // fp16 hs (one type at a time), 200K x 64 halves
  float* aU  = alloc((size_t)kNUser * 32);   // 8 planes x [N][4]
  float* aA  = alloc((size_t)kNArt * 16);    // 4 planes
  float* aC  = alloc((size_t)kNCat * 16);    // 4 planes
  float* fold = alloc(16 * 2 * 256);
  float* bact = alloc(2 * 3 * 64);
  int* rowptrA = (int*)alloc(1001008);
  int* rowsA   = (int*)alloc(4200000);
  int* tmp_row = (int*)alloc(1000000);
  int* tmp_col = (int*)alloc(1000000);
  int* blockhist = (int*)alloc(200704);
  int* binbase   = (int*)alloc(1032);
  int* bsum      = (int*)alloc(1024);

  uint32_t* hs16 = (uint32_t*)hsf;

  int* rowptr_t[8]; int* rows_t[8];
  {
    size_t ro = 0, eo = 0;
    for (int t = 0; t < 8; ++t) {
      int Nd = NSZ[EDST[t]];
      rowptr_t[t] = rowptrA + ro; ro += (size_t)Nd + 1;
      rows_t[t]   = rowsA + eo;   eo += (size_t)ECNT[t];
    }
  }

  // per-slot planes: user [t0s,t2s,t3s,t6s, t1d,t2d,t3d,t7d];
  // art [t1s,t4s, t0d,t5d]; cat [t5s,t7s, t4d,t6d]
  const size_t PU = (size_t)kNUser * 4, PA = (size_t)kNArt * 4, PC = (size_t)kNCat * 4;
  float* aSp[8] = {aU + 0 * PU, aA + 0 * PA, aU + 1 * PU, aU + 2 * PU,
                   aA + 1 * PA, aC + 0 * PC, aU + 3 * PU, aC + 1 * PC};
  float* aDp[8] = {aA + 2 * PA, aU + 4 * PU, aU + 5 * PU, aU + 6 * PU,
                   aC + 2 * PC, aA + 3 * PA, aC + 3 * PC, aU + 7 * PU};

  // ---- fold attention vectors + summed biases ----
  k_fold<<<16, 256, 0, stream>>>(Wsrc, Wdst, attS, attD, fold);
  k_bsum<<<2, 192, 0, stream>>>(bias, bact);

  // ---- CSR build: two-level LDS multisplit (no global atomics) ----
  for (int t = 0; t < 8; ++t) {
    int Nd = NSZ[EDST[t]], E = ECNT[t];
    const int* row = ei[t];
    const int* col = ei[t] + E;
    int shift = (Nd <= 1024) ? 0 : 8;
    int nbin = ((Nd - 1) >> shift) + 1;
    int nblk = (E + CHUNK - 1) / CHUNK;
    int n = nbin * nblk;
    int nb2 = (n + 4095) / 4096;
    k_bhist<<<nblk, 256, 0, stream>>>(col, E, nblk, nbin, shift, blockhist);
    k_s1<<<nb2, 256, 0, stream>>>(blockhist, bsum, n);
    k_s2<<<1, 1024, 0, stream>>>(bsum, nb2);
    k_s3<<<nb2, 256, 0, stream>>>(blockhist, bsum, n);
    k_binbase<<<(nbin + 256) / 256, 256, 0, stream>>>(blockhist, nblk, nbin, E, binbase);
    if (shift == 0) {
      k_bscat<<<nblk, 256, 0, stream>>>(row, col, E, nblk, nbin, 0,
                                        blockhist, rows_t[t], nullptr);
      k_rp<<<(Nd + 256) / 256, 256, 0, stream>>>(binbase, rowptr_t[t], Nd);
    } else {
      k_bscat<<<nblk, 256, 0, stream>>>(row, col, E, nblk, nbin, 8,
                                        blockhist, tmp_row, tmp_col);
      k_fine<<<nbin, 256, 0, stream>>>(tmp_row, tmp_col, binbase,
                                       rowptr_t[t], rows_t[t], Nd, nbin);
    }
  }

  float* xb[2][3] = {{xb0, xb0 + SZ_U, xb0 + SZ_U + SZ_A},
                     {xb1, xb1 + SZ_U, xb1 + SZ_U + SZ_A}};
  const float* xcur[3] = {x0[0], x0[1], x0[2]};
  for (int l = 0; l < 2; ++l) {
    // fold-slot id for (t, sd): ((l*8+t)*2 + sd)
    auto F = [&](int t, int sd) { return (l * 8 + t) * 2 + sd; };
    int4 ua = make_int4(F(0, 0), F(2, 0), F(3, 0), F(6, 0));
    int4 ub = make_int4(F(1, 1), F(2, 1), F(3, 1), F(7, 1));
    int4 aa = make_int4(F(1, 0), F(4, 0), F(0, 1), F(5, 1));
    int4 ca = make_int4(F(5, 0), F(7, 0), F(4, 1), F(6, 1));
    k_attn<8><<<(kNUser + 255) / 256, 256, 0, stream>>>(xcur[0], fold, ua, ub, aU, kNUser);
    k_attn<4><<<(kNArt + 255) / 256, 256, 0, stream>>>(xcur[1], fold, aa, aa, aA, kNArt);
    k_attn<4><<<(kNCat + 255) / 256, 256, 0, stream>>>(xcur[2], fold, ca, ca, aC, kNCat);

    for (int t = 0; t < 8; ++t) {
      int s = ESRC[t], d = EDST[t];
      int Ns = NSZ[s], Nd = NSZ[d];
      const float* Wt = Wsrc + (size_t)(l * 8 + t) * 4096;
      int mode = MODE[t];
      const float* ba = (mode == 2) ? bact + ((size_t)l * 3 + d) * 64 : nullptr;
      k_trans<<<(Ns + 63) / 64, 256, 0, stream>>>(xcur[s], Wt, hs16, Ns);
      if (Nd <= 512)
        k_gB<<<Nd, 256, 0, stream>>>(rowptr_t[t], rows_t[t], aSp[t], aDp[t],
                                     hs16, xb[l][d], mode, ba);
      else
        k_g16<<<(Nd + 15) / 16, 256, 0, stream>>>(rowptr_t[t], rows_t[t], aSp[t], aDp[t],
                                                  hs16, xb[l][d], Nd, mode, ba);
    }
    xcur[0] = xb[l][0]; xcur[1] = xb[l][1]; xcur[2] = xb[l][2];
  }
  k_final<<<((int)SZ_U + 255) / 256, 256, 0, stream>>>(x0[0], xb[0][0], xb[1][0], (float*)d_out, (int)SZ_U);
  k_final<<<((int)SZ_A + 255) / 256, 256, 0, stream>>>(x0[1], xb[0][1], xb[1][1], (float*)d_out + SZ_U, (int)SZ_A);
}